// Round 2
// baseline (655.779 us; speedup 1.0000x reference)
//
#include <hip/hip_runtime.h>

#define IN_CH 128
#define HID 64
#define OUT_CH 16

// ---------------- util ----------------

__global__ void k_zero(float* __restrict__ p, long long n) {
    long long i = (long long)blockIdx.x * blockDim.x + threadIdx.x;
    if (i < n) p[i] = 0.0f;
}

// ---------------- degree / norm ----------------

__global__ void k_init_deg(float* __restrict__ deg, int n) {
    int i = blockIdx.x * blockDim.x + threadIdx.x;
    if (i < n) deg[i] = 1.0f;  // self-loop contributes 1
}

__global__ void k_count_deg(const int* __restrict__ ei, float* __restrict__ deg, int E) {
    int e = blockIdx.x * blockDim.x + threadIdx.x;
    if (e < E) {
        int d = ei[E + e];  // row 1 = dst
        atomicAdd(&deg[d], 1.0f);
    }
}

__global__ void k_dinv(float* __restrict__ dinv, int n) {
    int i = blockIdx.x * blockDim.x + threadIdx.x;
    if (i < n) dinv[i] = rsqrtf(dinv[i]);  // deg >= 1 always (self-loop)
}

// ---------------- layer 1 ----------------

// xl = x @ W1   [N,128]@[128,64] -> [N,64]; 4 nodes per 256-thread block
__global__ __launch_bounds__(256) void k_gemm1(const float* __restrict__ x,
                                               const float* __restrict__ W,
                                               float* __restrict__ xl, int n) {
    __shared__ float sx[4][IN_CH];
    int node0 = blockIdx.x * 4;
    int tid = threadIdx.x;
    for (int t = tid; t < 4 * IN_CH; t += 256) {
        int r = t >> 7, k = t & (IN_CH - 1);
        int node = node0 + r;
        sx[r][k] = (node < n) ? x[(size_t)node * IN_CH + k] : 0.0f;
    }
    __syncthreads();
    int r = tid >> 6;   // node within block
    int j = tid & 63;   // output channel
    int node = node0 + r;
    if (node >= n) return;
    float acc = 0.0f;
#pragma unroll 8
    for (int k = 0; k < IN_CH; ++k)
        acc += sx[r][k] * W[k * HID + j];
    xl[(size_t)node * HID + j] = acc;
}

// scatter: agg[dst,c] += dinv[s]*dinv[d] * xl[src,c]; one edge per wave (64 ch)
__global__ __launch_bounds__(256) void k_edge1(const int* __restrict__ ei,
                                               const float* __restrict__ dinv,
                                               const float* __restrict__ xl,
                                               float* __restrict__ agg, int E) {
    long long tid = (long long)blockIdx.x * blockDim.x + threadIdx.x;
    int e = (int)(tid >> 6);
    int c = (int)(tid & 63);
    if (e >= E) return;
    int s = ei[e];
    int d = ei[E + e];
    float norm = dinv[s] * dinv[d];
    atomicAdd(&agg[(size_t)d * HID + c], norm * xl[(size_t)s * HID + c]);
}

// h = relu(agg + dinv^2 * xl + b1)  (in place over agg)
__global__ void k_epilogue1(float* __restrict__ agg, const float* __restrict__ xl,
                            const float* __restrict__ dinv, const float* __restrict__ b,
                            int n) {
    int idx = blockIdx.x * blockDim.x + threadIdx.x;
    if (idx >= n * HID) return;
    int i = idx >> 6;
    int c = idx & 63;
    float di = dinv[i];
    float v = agg[idx] + di * di * xl[idx] + b[c];
    agg[idx] = fmaxf(v, 0.0f);
}

// ---------------- layer 2 ----------------

// hl = h @ W2  [N,64]@[64,16] -> [N,16]; 16 nodes per 256-thread block
__global__ __launch_bounds__(256) void k_gemm2(const float* __restrict__ h,
                                               const float* __restrict__ W,
                                               float* __restrict__ hl, int n) {
    __shared__ float sW[HID * OUT_CH];  // 4 KB
    __shared__ float sh[16][HID];
    int tid = threadIdx.x;
    for (int t = tid; t < HID * OUT_CH; t += 256) sW[t] = W[t];
    int node0 = blockIdx.x * 16;
    for (int t = tid; t < 16 * HID; t += 256) {
        int r = t >> 6, k = t & 63;
        int node = node0 + r;
        sh[r][k] = (node < n) ? h[(size_t)node * HID + k] : 0.0f;
    }
    __syncthreads();
    int r = tid >> 4, j = tid & 15;
    int node = node0 + r;
    if (node >= n) return;
    float acc = 0.0f;
#pragma unroll
    for (int k = 0; k < HID; ++k)
        acc += sh[r][k] * sW[k * OUT_CH + j];
    hl[(size_t)node * OUT_CH + j] = acc;
}

// scatter: out[dst,c] += norm * hl[src,c]; 4 edges per wave (16 ch each)
__global__ __launch_bounds__(256) void k_edge2(const int* __restrict__ ei,
                                               const float* __restrict__ dinv,
                                               const float* __restrict__ hl,
                                               float* __restrict__ out, int E) {
    long long tid = (long long)blockIdx.x * blockDim.x + threadIdx.x;
    int e = (int)(tid >> 4);
    int c = (int)(tid & 15);
    if (e >= E) return;
    int s = ei[e];
    int d = ei[E + e];
    float norm = dinv[s] * dinv[d];
    atomicAdd(&out[(size_t)d * OUT_CH + c], norm * hl[(size_t)s * OUT_CH + c]);
}

// out += dinv^2 * hl + b2
__global__ void k_epilogue2(float* __restrict__ out, const float* __restrict__ hl,
                            const float* __restrict__ dinv, const float* __restrict__ b,
                            int n) {
    int idx = blockIdx.x * blockDim.x + threadIdx.x;
    if (idx >= n * OUT_CH) return;
    int i = idx >> 4;
    int c = idx & 15;
    float di = dinv[i];
    out[idx] = out[idx] + di * di * hl[idx] + b[c];
}

extern "C" void kernel_launch(void* const* d_in, const int* in_sizes, int n_in,
                              void* d_out, int out_size, void* d_ws, size_t ws_size,
                              hipStream_t stream) {
    const float* x  = (const float*)d_in[0];
    const int* ei   = (const int*)d_in[1];   // harness delivers integers as int32
    const float* W1 = (const float*)d_in[2];
    const float* b1 = (const float*)d_in[3];
    const float* W2 = (const float*)d_in[4];
    const float* b2 = (const float*)d_in[5];
    float* out = (float*)d_out;

    const int n = in_sizes[0] / IN_CH;   // 100000
    const int E = in_sizes[1] / 2;       // 1600000

    // workspace layout (floats); total = n*(1+64+64+16)*4 B = 58.0 MB
    float* ws   = (float*)d_ws;
    float* dinv = ws;                        // n  (deg computed in place)
    float* xl   = dinv + n;                  // n*64
    float* agg1 = xl + (size_t)n * HID;      // n*64  (becomes h in place)
    float* hl   = agg1 + (size_t)n * HID;    // n*16

    // degree + dinv (in place)
    k_init_deg<<<(n + 255) / 256, 256, 0, stream>>>(dinv, n);
    k_count_deg<<<(E + 255) / 256, 256, 0, stream>>>(ei, dinv, E);
    k_dinv<<<(n + 255) / 256, 256, 0, stream>>>(dinv, n);

    // layer 1
    k_gemm1<<<(n + 3) / 4, 256, 0, stream>>>(x, W1, xl, n);
    {
        long long tot = (long long)n * HID;
        k_zero<<<(int)((tot + 255) / 256), 256, 0, stream>>>(agg1, tot);
    }
    {
        long long total = (long long)E * HID;
        k_edge1<<<(int)((total + 255) / 256), 256, 0, stream>>>(ei, dinv, xl, agg1, E);
    }
    k_epilogue1<<<(n * HID + 255) / 256, 256, 0, stream>>>(agg1, xl, dinv, b1, n);

    // layer 2
    k_gemm2<<<(n + 15) / 16, 256, 0, stream>>>(agg1, W2, hl, n);
    {
        long long tot = (long long)n * OUT_CH;
        k_zero<<<(int)((tot + 255) / 256), 256, 0, stream>>>(out, tot);
    }
    {
        long long total = (long long)E * OUT_CH;
        k_edge2<<<(int)((total + 255) / 256), 256, 0, stream>>>(ei, dinv, hl, out, E);
    }
    k_epilogue2<<<(n * OUT_CH + 255) / 256, 256, 0, stream>>>(out, hl, dinv, b2, n);
}

// Round 3
// 534.547 us; speedup vs baseline: 1.2268x; 1.2268x over previous
//
#include <hip/hip_runtime.h>

#define IN_CH 128
#define HID 64
#define OUT_CH 16

// ---------------- CSR build ----------------

__global__ void k_zero_int(int* __restrict__ p, int n) {
    int i = blockIdx.x * blockDim.x + threadIdx.x;
    if (i < n) p[i] = 0;
}

__global__ void k_count(const int* __restrict__ ei, int* __restrict__ counts, int E) {
    int e = blockIdx.x * blockDim.x + threadIdx.x;
    if (e < E) atomicAdd(&counts[ei[E + e]], 1);  // row 1 = dst
}

// dinv[i] = rsqrt(counts[i] + 1)   (+1 = self-loop)
__global__ void k_dinv(const int* __restrict__ counts, float* __restrict__ dinv, int n) {
    int i = blockIdx.x * blockDim.x + threadIdx.x;
    if (i < n) dinv[i] = rsqrtf((float)(counts[i] + 1));
}

// in-place exclusive scan, phase 1: per-block scan (256 elems/block)
__global__ __launch_bounds__(256) void k_scan_local(int* __restrict__ data,
                                                    int* __restrict__ blk_sum, int n) {
    __shared__ int s[256];
    int i = blockIdx.x * 256 + threadIdx.x;
    int v = (i < n) ? data[i] : 0;
    s[threadIdx.x] = v;
    __syncthreads();
    for (int off = 1; off < 256; off <<= 1) {
        int t = (threadIdx.x >= off) ? s[threadIdx.x - off] : 0;
        __syncthreads();
        s[threadIdx.x] += t;
        __syncthreads();
    }
    if (i < n) data[i] = s[threadIdx.x] - v;  // exclusive within block
    if (threadIdx.x == 255) blk_sum[blockIdx.x] = s[255];
}

// phase 2: single-block exclusive scan of block sums (nblk <= 512)
__global__ __launch_bounds__(256) void k_scan_blocks(int* __restrict__ blk, int nblk) {
    __shared__ int s[256];
    __shared__ int sh_carry;
    if (threadIdx.x == 0) sh_carry = 0;
    __syncthreads();
    for (int base = 0; base < nblk; base += 256) {
        int carry = sh_carry;
        int i = base + threadIdx.x;
        int v = (i < nblk) ? blk[i] : 0;
        s[threadIdx.x] = v;
        __syncthreads();
        for (int off = 1; off < 256; off <<= 1) {
            int t = (threadIdx.x >= off) ? s[threadIdx.x - off] : 0;
            __syncthreads();
            s[threadIdx.x] += t;
            __syncthreads();
        }
        if (i < nblk) blk[i] = carry + s[threadIdx.x] - v;
        if (threadIdx.x == 255) sh_carry = carry + s[255];
        __syncthreads();
    }
}

// phase 3: add block offsets; also init cursor = row_ptr
__global__ void k_scan_add(int* __restrict__ row_ptr, const int* __restrict__ blk,
                           int* __restrict__ cursor, int n) {
    int i = blockIdx.x * blockDim.x + threadIdx.x;
    if (i < n) {
        int r = row_ptr[i] + blk[blockIdx.x];
        row_ptr[i] = r;
        cursor[i] = r;
    }
}

// scatter src ids into dst-sorted order; afterwards cursor[d] = segment end
__global__ void k_scatter(const int* __restrict__ ei, int* __restrict__ cursor,
                          int* __restrict__ esrc, int E) {
    int e = blockIdx.x * blockDim.x + threadIdx.x;
    if (e < E) {
        int d = ei[E + e];
        int pos = atomicAdd(&cursor[d], 1);
        esrc[pos] = ei[e];
    }
}

// ---------------- layer 1 ----------------

// xl = x @ W1   [N,128]@[128,64] -> [N,64]; 4 nodes per 256-thread block
__global__ __launch_bounds__(256) void k_gemm1(const float* __restrict__ x,
                                               const float* __restrict__ W,
                                               float* __restrict__ xl, int n) {
    __shared__ float sx[4][IN_CH];
    int node0 = blockIdx.x * 4;
    int tid = threadIdx.x;
    for (int t = tid; t < 4 * IN_CH; t += 256) {
        int r = t >> 7, k = t & (IN_CH - 1);
        int node = node0 + r;
        sx[r][k] = (node < n) ? x[(size_t)node * IN_CH + k] : 0.0f;
    }
    __syncthreads();
    int r = tid >> 6, j = tid & 63;
    int node = node0 + r;
    if (node >= n) return;
    float acc = 0.0f;
#pragma unroll 8
    for (int k = 0; k < IN_CH; ++k)
        acc += sx[r][k] * W[k * HID + j];
    xl[(size_t)node * HID + j] = acc;
}

// gather-aggregate + self-loop + bias + relu, fused. One wave per dst node.
__global__ __launch_bounds__(256) void k_agg1(const int* __restrict__ row_ptr,
                                              const int* __restrict__ row_end,
                                              const int* __restrict__ esrc,
                                              const float* __restrict__ dinv,
                                              const float* __restrict__ xl,
                                              const float* __restrict__ b,
                                              float* __restrict__ h, int n) {
    int d = (int)(((long long)blockIdx.x * 256 + threadIdx.x) >> 6);
    int c = threadIdx.x & 63;
    if (d >= n) return;
    float dd = dinv[d];
    float acc = 0.0f;
    int j0 = row_ptr[d], j1 = row_end[d];
    for (int j = j0; j < j1; ++j) {
        int s = esrc[j];                       // broadcast across wave
        float nrm = dinv[s] * dd;              // broadcast
        acc += nrm * xl[(size_t)s * HID + c];  // coalesced 256B row
    }
    float v = acc + dd * dd * xl[(size_t)d * HID + c] + b[c];
    h[(size_t)d * HID + c] = fmaxf(v, 0.0f);
}

// ---------------- layer 2 ----------------

// hl = h @ W2  [N,64]@[64,16] -> [N,16]; 16 nodes per 256-thread block
__global__ __launch_bounds__(256) void k_gemm2(const float* __restrict__ h,
                                               const float* __restrict__ W,
                                               float* __restrict__ hl, int n) {
    __shared__ float sW[HID * OUT_CH];
    __shared__ float sh[16][HID];
    int tid = threadIdx.x;
    for (int t = tid; t < HID * OUT_CH; t += 256) sW[t] = W[t];
    int node0 = blockIdx.x * 16;
    for (int t = tid; t < 16 * HID; t += 256) {
        int r = t >> 6, k = t & 63;
        int node = node0 + r;
        sh[r][k] = (node < n) ? h[(size_t)node * HID + k] : 0.0f;
    }
    __syncthreads();
    int r = tid >> 4, j = tid & 15;
    int node = node0 + r;
    if (node >= n) return;
    float acc = 0.0f;
#pragma unroll
    for (int k = 0; k < HID; ++k)
        acc += sh[r][k] * sW[k * OUT_CH + j];
    hl[(size_t)node * OUT_CH + j] = acc;
}

// gather-aggregate + self-loop + bias, fused. One 16-lane group per dst node.
__global__ __launch_bounds__(256) void k_agg2(const int* __restrict__ row_ptr,
                                              const int* __restrict__ row_end,
                                              const int* __restrict__ esrc,
                                              const float* __restrict__ dinv,
                                              const float* __restrict__ hl,
                                              const float* __restrict__ b,
                                              float* __restrict__ out, int n) {
    int d = (int)(((long long)blockIdx.x * 256 + threadIdx.x) >> 4);
    int c = threadIdx.x & 15;
    if (d >= n) return;
    float dd = dinv[d];
    float acc = 0.0f;
    int j0 = row_ptr[d], j1 = row_end[d];
    for (int j = j0; j < j1; ++j) {
        int s = esrc[j];
        float nrm = dinv[s] * dd;
        acc += nrm * hl[(size_t)s * OUT_CH + c];  // coalesced 64B row
    }
    out[(size_t)d * OUT_CH + c] = acc + dd * dd * hl[(size_t)d * OUT_CH + c] + b[c];
}

extern "C" void kernel_launch(void* const* d_in, const int* in_sizes, int n_in,
                              void* d_out, int out_size, void* d_ws, size_t ws_size,
                              hipStream_t stream) {
    const float* x  = (const float*)d_in[0];
    const int* ei   = (const int*)d_in[1];   // int32 from harness
    const float* W1 = (const float*)d_in[2];
    const float* b1 = (const float*)d_in[3];
    const float* W2 = (const float*)d_in[4];
    const float* b2 = (const float*)d_in[5];
    float* out = (float*)d_out;

    const int n = in_sizes[0] / IN_CH;   // 100000
    const int E = in_sizes[1] / 2;       // 1600000
    const int nblk = (n + 255) / 256;    // 391

    // workspace layout: (131n + E + 512)*4 B ~= 58.8 MB
    int* counts = (int*)d_ws;            // n ints; becomes row_ptr in place
    int* cursor = counts + n;            // n ints; becomes row_end after scatter
    int* blk    = cursor + n;            // 512 ints
    int* esrc   = blk + 512;             // E ints (dst-sorted src ids)
    float* dinv = (float*)(esrc + E);    // n
    float* xl   = dinv + n;              // n*64 ; later aliased as hl (n*16)
    float* h    = xl + (size_t)n * HID;  // n*64
    float* hl   = xl;                    // alias: xl dead after k_agg1

    // --- CSR build ---
    k_zero_int<<<nblk, 256, 0, stream>>>(counts, n);
    k_count<<<(E + 255) / 256, 256, 0, stream>>>(ei, counts, E);
    k_dinv<<<nblk, 256, 0, stream>>>(counts, dinv, n);
    k_scan_local<<<nblk, 256, 0, stream>>>(counts, blk, n);
    k_scan_blocks<<<1, 256, 0, stream>>>(blk, nblk);
    k_scan_add<<<nblk, 256, 0, stream>>>(counts, blk, cursor, n);
    k_scatter<<<(E + 255) / 256, 256, 0, stream>>>(ei, cursor, esrc, E);
    // now: counts = row_ptr, cursor = row_end

    // --- layer 1 ---
    k_gemm1<<<(n + 3) / 4, 256, 0, stream>>>(x, W1, xl, n);
    k_agg1<<<(int)(((long long)n * HID + 255) / 256), 256, 0, stream>>>(
        counts, cursor, esrc, dinv, xl, b1, h, n);

    // --- layer 2 ---
    k_gemm2<<<(n + 15) / 16, 256, 0, stream>>>(h, W2, hl, n);
    k_agg2<<<(int)(((long long)n * OUT_CH + 255) / 256), 256, 0, stream>>>(
        counts, cursor, esrc, dinv, hl, b2, out, n);
}

// Round 4
// 388.219 us; speedup vs baseline: 1.6892x; 1.3769x over previous
//
#include <hip/hip_runtime.h>

#define IN_CH 128
#define HID 64
#define OUT_CH 16

// ---------------- CSR build ----------------

__global__ void k_zero_int(int* __restrict__ p, int n) {
    int i = blockIdx.x * blockDim.x + threadIdx.x;
    if (i < n) p[i] = 0;
}

__global__ void k_count(const int* __restrict__ ei, int* __restrict__ counts, int E) {
    int e = blockIdx.x * blockDim.x + threadIdx.x;
    if (e < E) atomicAdd(&counts[ei[E + e]], 1);  // row 1 = dst
}

// phase 1: per-block exclusive scan of counts (in place) + fused dinv = rsqrt(count+1)
__global__ __launch_bounds__(256) void k_scan_local(int* __restrict__ data,
                                                    int* __restrict__ blk_sum,
                                                    float* __restrict__ dinv, int n) {
    __shared__ int s[256];
    int i = blockIdx.x * 256 + threadIdx.x;
    int v = (i < n) ? data[i] : 0;
    if (i < n) dinv[i] = rsqrtf((float)(v + 1));  // +1 = self-loop
    s[threadIdx.x] = v;
    __syncthreads();
    for (int off = 1; off < 256; off <<= 1) {
        int t = (threadIdx.x >= off) ? s[threadIdx.x - off] : 0;
        __syncthreads();
        s[threadIdx.x] += t;
        __syncthreads();
    }
    if (i < n) data[i] = s[threadIdx.x] - v;  // exclusive within block
    if (threadIdx.x == 255) blk_sum[blockIdx.x] = s[255];
}

// phase 2: single-block exclusive scan of block sums
__global__ __launch_bounds__(256) void k_scan_blocks(int* __restrict__ blk, int nblk) {
    __shared__ int s[256];
    __shared__ int sh_carry;
    if (threadIdx.x == 0) sh_carry = 0;
    __syncthreads();
    for (int base = 0; base < nblk; base += 256) {
        int carry = sh_carry;
        int i = base + threadIdx.x;
        int v = (i < nblk) ? blk[i] : 0;
        s[threadIdx.x] = v;
        __syncthreads();
        for (int off = 1; off < 256; off <<= 1) {
            int t = (threadIdx.x >= off) ? s[threadIdx.x - off] : 0;
            __syncthreads();
            s[threadIdx.x] += t;
            __syncthreads();
        }
        if (i < nblk) blk[i] = carry + s[threadIdx.x] - v;
        if (threadIdx.x == 255) sh_carry = carry + s[255];
        __syncthreads();
    }
}

// phase 3: add block offsets; init cursor = row_ptr
__global__ void k_scan_add(int* __restrict__ row_ptr, const int* __restrict__ blk,
                           int* __restrict__ cursor, int n) {
    int i = blockIdx.x * blockDim.x + threadIdx.x;
    if (i < n) {
        int r = row_ptr[i] + blk[blockIdx.x];
        row_ptr[i] = r;
        cursor[i] = r;
    }
}

// scatter src ids dst-sorted; afterwards cursor[d] = segment end
__global__ void k_scatter(const int* __restrict__ ei, int* __restrict__ cursor,
                          int* __restrict__ esrc, int E) {
    int e = blockIdx.x * blockDim.x + threadIdx.x;
    if (e < E) {
        int d = ei[E + e];
        int pos = atomicAdd(&cursor[d], 1);
        esrc[pos] = ei[e];
    }
}

// ---------------- layer 1 ----------------

// xlp = dinv * (x @ W1)  [N,128]@[128,64]; 8 nodes/block, 2 nodes/thread
__global__ __launch_bounds__(256) void k_gemm1(const float* __restrict__ x,
                                               const float* __restrict__ W,
                                               const float* __restrict__ dinv,
                                               float* __restrict__ xlp, int n) {
    __shared__ float sx[8][IN_CH];  // 4 KB
    int node0 = blockIdx.x * 8;
    int tid = threadIdx.x;
    {   // 8*128 floats = 256 float4, one per thread
        int r = tid >> 5, k4 = tid & 31;
        int node = node0 + r;
        float4 v = (node < n) ? ((const float4*)(x + (size_t)node * IN_CH))[k4]
                              : make_float4(0.f, 0.f, 0.f, 0.f);
        ((float4*)sx[r])[k4] = v;
    }
    __syncthreads();
    int r = tid >> 6, j = tid & 63;
    float acc0 = 0.f, acc1 = 0.f;
#pragma unroll 8
    for (int k = 0; k < IN_CH; ++k) {
        float w = W[k * HID + j];
        acc0 += sx[r][k] * w;
        acc1 += sx[r + 4][k] * w;
    }
    int nodeA = node0 + r, nodeB = node0 + r + 4;
    if (nodeA < n) xlp[(size_t)nodeA * HID + j] = dinv[nodeA] * acc0;
    if (nodeB < n) xlp[(size_t)nodeB * HID + j] = dinv[nodeB] * acc1;
}

// h[d] = relu(dd * (sum_s xlp[s] + xlp[d]) + b1). One wave per dst; 4-edge unroll.
__global__ __launch_bounds__(256) void k_agg1(const int* __restrict__ row_ptr,
                                              const int* __restrict__ row_end,
                                              const int* __restrict__ esrc,
                                              const float* __restrict__ dinv,
                                              const float* __restrict__ xlp,
                                              const float* __restrict__ b,
                                              float* __restrict__ h, int n) {
    int d = blockIdx.x * 4 + (threadIdx.x >> 6);
    int c = threadIdx.x & 63;
    if (d >= n) return;
    int j0 = row_ptr[d], j1 = row_end[d];
    float acc = 0.f;
    int j = j0;
    for (; j + 4 <= j1; j += 4) {
        int s0 = esrc[j], s1 = esrc[j + 1], s2 = esrc[j + 2], s3 = esrc[j + 3];
        float v0 = xlp[(size_t)s0 * HID + c];
        float v1 = xlp[(size_t)s1 * HID + c];
        float v2 = xlp[(size_t)s2 * HID + c];
        float v3 = xlp[(size_t)s3 * HID + c];
        acc += (v0 + v1) + (v2 + v3);
    }
    for (; j < j1; ++j) acc += xlp[(size_t)esrc[j] * HID + c];
    float dd = dinv[d];
    float v = dd * (acc + xlp[(size_t)d * HID + c]) + b[c];
    h[(size_t)d * HID + c] = fmaxf(v, 0.f);
}

// ---------------- layer 2 ----------------

// hlp = dinv * (h @ W2)  [N,64]@[64,16]; 16 nodes/block
__global__ __launch_bounds__(256) void k_gemm2(const float* __restrict__ h,
                                               const float* __restrict__ W,
                                               const float* __restrict__ dinv,
                                               float* __restrict__ hlp, int n) {
    __shared__ float sW[HID * OUT_CH];
    __shared__ float sh[16][HID];
    int tid = threadIdx.x;
    for (int t = tid; t < HID * OUT_CH; t += 256) sW[t] = W[t];
    int node0 = blockIdx.x * 16;
    for (int t = tid; t < 16 * HID / 4; t += 256) {
        int r = t >> 4, k4 = t & 15;
        int node = node0 + r;
        float4 v = (node < n) ? ((const float4*)(h + (size_t)node * HID))[k4]
                              : make_float4(0.f, 0.f, 0.f, 0.f);
        ((float4*)sh[r])[k4] = v;
    }
    __syncthreads();
    int r = tid >> 4, j = tid & 15;
    int node = node0 + r;
    if (node >= n) return;
    float acc = 0.f;
#pragma unroll
    for (int k = 0; k < HID; ++k)
        acc += sh[r][k] * sW[k * OUT_CH + j];
    hlp[(size_t)node * OUT_CH + j] = dinv[node] * acc;
}

// out[d] = dd * (sum_s hlp[s] + hlp[d]) + b2. One 16-lane group per dst; 4-edge unroll.
__global__ __launch_bounds__(256) void k_agg2(const int* __restrict__ row_ptr,
                                              const int* __restrict__ row_end,
                                              const int* __restrict__ esrc,
                                              const float* __restrict__ dinv,
                                              const float* __restrict__ hlp,
                                              const float* __restrict__ b,
                                              float* __restrict__ out, int n) {
    int d = blockIdx.x * 16 + (threadIdx.x >> 4);
    int c = threadIdx.x & 15;
    if (d >= n) return;
    int j0 = row_ptr[d], j1 = row_end[d];
    float acc = 0.f;
    int j = j0;
    for (; j + 4 <= j1; j += 4) {
        int s0 = esrc[j], s1 = esrc[j + 1], s2 = esrc[j + 2], s3 = esrc[j + 3];
        float v0 = hlp[(size_t)s0 * OUT_CH + c];
        float v1 = hlp[(size_t)s1 * OUT_CH + c];
        float v2 = hlp[(size_t)s2 * OUT_CH + c];
        float v3 = hlp[(size_t)s3 * OUT_CH + c];
        acc += (v0 + v1) + (v2 + v3);
    }
    for (; j < j1; ++j) acc += hlp[(size_t)esrc[j] * OUT_CH + c];
    float dd = dinv[d];
    out[(size_t)d * OUT_CH + c] = dd * (acc + hlp[(size_t)d * OUT_CH + c]) + b[c];
}

extern "C" void kernel_launch(void* const* d_in, const int* in_sizes, int n_in,
                              void* d_out, int out_size, void* d_ws, size_t ws_size,
                              hipStream_t stream) {
    const float* x  = (const float*)d_in[0];
    const int* ei   = (const int*)d_in[1];   // int32 from harness
    const float* W1 = (const float*)d_in[2];
    const float* b1 = (const float*)d_in[3];
    const float* W2 = (const float*)d_in[4];
    const float* b2 = (const float*)d_in[5];
    float* out = (float*)d_out;

    const int n = in_sizes[0] / IN_CH;   // 100000
    const int E = in_sizes[1] / 2;       // 1600000
    const int nblk = (n + 255) / 256;    // 391

    // workspace: (131n + E + 512)*4 B ~= 58.8 MB
    int* counts = (int*)d_ws;            // n; becomes row_ptr in place
    int* cursor = counts + n;            // n; becomes row_end after scatter
    int* blk    = cursor + n;            // 512
    int* esrc   = blk + 512;             // E (dst-sorted src ids)
    float* dinv = (float*)(esrc + E);    // n
    float* xlp  = dinv + n;              // n*64 ; later aliased as hlp (n*16)
    float* h    = xlp + (size_t)n * HID; // n*64
    float* hlp  = xlp;                   // alias: xlp dead after k_agg1

    // --- CSR build ---
    k_zero_int<<<nblk, 256, 0, stream>>>(counts, n);
    k_count<<<(E + 255) / 256, 256, 0, stream>>>(ei, counts, E);
    k_scan_local<<<nblk, 256, 0, stream>>>(counts, blk, dinv, n);
    k_scan_blocks<<<1, 256, 0, stream>>>(blk, nblk);
    k_scan_add<<<nblk, 256, 0, stream>>>(counts, blk, cursor, n);
    k_scatter<<<(E + 255) / 256, 256, 0, stream>>>(ei, cursor, esrc, E);
    // now: counts = row_ptr, cursor = row_end

    // --- layer 1 ---
    k_gemm1<<<(n + 7) / 8, 256, 0, stream>>>(x, W1, dinv, xlp, n);
    k_agg1<<<(n + 3) / 4, 256, 0, stream>>>(counts, cursor, esrc, dinv, xlp, b1, h, n);

    // --- layer 2 ---
    k_gemm2<<<(n + 15) / 16, 256, 0, stream>>>(h, W2, dinv, hlp, n);
    k_agg2<<<(n + 15) / 16, 256, 0, stream>>>(counts, cursor, esrc, dinv, hlp, b2, out, n);
}